// Round 8
// baseline (335.392 us; speedup 1.0000x reference)
//
#include <hip/hip_runtime.h>
#include <cstddef>
#include <cstdint>

#define D_MODEL 1024
#define D_STATE 8
#define D_INNER 1536
#define SEQ_L   2048
#define BATCH   4
#define MROWS   (BATCH * SEQ_L)   // 8192

// chunked scan: 16 chunks of 128, warmup 64 (|decay|<=0.55 -> 0.55^64 ~ 2.5e-17)
#define SCAN_CL 128
#define SCAN_W  64
#define SCAN_C  (SEQ_L / SCAN_CL)   // 16

typedef __attribute__((ext_vector_type(8))) short short8;
typedef __attribute__((ext_vector_type(4))) float f32x4;
typedef unsigned int u32;
typedef unsigned short u16;

__device__ __forceinline__ u16 bf_rn(float x) {   // fp32 -> bf16, round-nearest-even
  u32 b = __float_as_uint(x);
  return (u16)((b + 0x7FFFu + ((b >> 16) & 1u)) >> 16);
}
__device__ __forceinline__ float bf_f(u16 h) {
  return __uint_as_float(((u32)h) << 16);
}
__device__ __forceinline__ void gload16(const void* g, void* l) {
  __builtin_amdgcn_global_load_lds((const __attribute__((address_space(1))) u32*)g,
                                   (__attribute__((address_space(3))) u32*)l, 16, 0, 0);
}

#define VMCNT0() asm volatile("s_waitcnt vmcnt(0)" ::: "memory")
#define VMCNT2() asm volatile("s_waitcnt vmcnt(2)" ::: "memory")
#define VMCNT4() asm volatile("s_waitcnt vmcnt(4)" ::: "memory")
#define VMCNT6() asm volatile("s_waitcnt vmcnt(6)" ::: "memory")
#define BARRIER()                                    \
  {                                                  \
    asm volatile("" ::: "memory");                   \
    __builtin_amdgcn_s_barrier();                    \
    asm volatile("" ::: "memory");                   \
  }

// --------------------------------------------- prep: LN-in split + weight split
// blockIdx.x < MROWS  : ln_split row
// blockIdx.x >= MROWS : weight-split, VECTORIZED x4 (float4 in, 2x ushort4 out)
__global__ __launch_bounds__(256) void prep_kernel(
    const float* __restrict__ x, const float* __restrict__ g,
    const float* __restrict__ b, u16* __restrict__ y0, u16* __restrict__ y1,
    const float* __restrict__ W1, u16* __restrict__ a0, u16* __restrict__ a1,
    int n14, const float* __restrict__ W2, u16* __restrict__ c0,
    u16* __restrict__ c1, int n24)
{
  const int bx = blockIdx.x;
  const int t = threadIdx.x;
  if (bx >= MROWS) {                      // ---- weight split (x4 vector) ----
    int i4 = (bx - MROWS) * 256 + t;
    const float* src;
    u16 *d0, *d1;
    int idx;
    if (i4 < n14)           { src = W1; d0 = a0; d1 = a1; idx = i4; }
    else if (i4 < n14 + n24){ src = W2; d0 = c0; d1 = c1; idx = i4 - n14; }
    else return;
    float4 v = reinterpret_cast<const float4*>(src)[idx];
    ushort4 h0, h1;
    u16 a;
    a = bf_rn(v.x); h0.x = a; h1.x = bf_rn(v.x - bf_f(a));
    a = bf_rn(v.y); h0.y = a; h1.y = bf_rn(v.y - bf_f(a));
    a = bf_rn(v.z); h0.z = a; h1.z = bf_rn(v.z - bf_f(a));
    a = bf_rn(v.w); h0.w = a; h1.w = bf_rn(v.w - bf_f(a));
    reinterpret_cast<ushort4*>(d0)[idx] = h0;
    reinterpret_cast<ushort4*>(d1)[idx] = h1;
    return;
  }
  // ---- LayerNorm-in -> 2-term bf16 planes ----
  const int row = bx;
  float4 v = reinterpret_cast<const float4*>(x + (size_t)row * D_MODEL)[t];
  float s  = v.x + v.y + v.z + v.w;
  float s2 = v.x * v.x + v.y * v.y + v.z * v.z + v.w * v.w;
  #pragma unroll
  for (int o = 32; o > 0; o >>= 1) {
    s  += __shfl_down(s, o);
    s2 += __shfl_down(s2, o);
  }
  __shared__ float ls[4], ls2[4];
  const int wid = t >> 6, lid = t & 63;
  if (lid == 0) { ls[wid] = s; ls2[wid] = s2; }
  __syncthreads();
  if (t == 0) {
    ls[0]  = ls[0] + ls[1] + ls[2] + ls[3];
    ls2[0] = ls2[0] + ls2[1] + ls2[2] + ls2[3];
  }
  __syncthreads();
  const float mean = ls[0] * (1.0f / D_MODEL);
  const float var  = ls2[0] * (1.0f / D_MODEL) - mean * mean;
  const float rstd = rsqrtf(var + 1e-5f);
  float4 gv = reinterpret_cast<const float4*>(g)[t];
  float4 bv = reinterpret_cast<const float4*>(b)[t];
  float o[4];
  o[0] = (v.x - mean) * rstd * gv.x + bv.x;
  o[1] = (v.y - mean) * rstd * gv.y + bv.y;
  o[2] = (v.z - mean) * rstd * gv.z + bv.z;
  o[3] = (v.w - mean) * rstd * gv.w + bv.w;
  ushort4 h0, h1;
  u16 a, c;
  a = bf_rn(o[0]); c = bf_rn(o[0] - bf_f(a)); h0.x = a; h1.x = c;
  a = bf_rn(o[1]); c = bf_rn(o[1] - bf_f(a)); h0.y = a; h1.y = c;
  a = bf_rn(o[2]); c = bf_rn(o[2] - bf_f(a)); h0.z = a; h1.z = c;
  a = bf_rn(o[3]); c = bf_rn(o[3] - bf_f(a)); h0.w = a; h1.w = c;
  reinterpret_cast<ushort4*>(y0 + (size_t)row * D_MODEL)[t] = h0;
  reinterpret_cast<ushort4*>(y1 + (size_t)row * D_MODEL)[t] = h1;
}

// LN over clip(pa+pb) — fuses GEMM2's split-K reduction + clip epilogue.
__global__ __launch_bounds__(256) void ln_sum_kernel(
    const float* __restrict__ xa, const float* __restrict__ xb,
    const float* __restrict__ g, const float* __restrict__ b,
    float* __restrict__ y)
{
  const int row = blockIdx.x;
  const int t = threadIdx.x;
  float4 va = reinterpret_cast<const float4*>(xa + (size_t)row * D_MODEL)[t];
  float4 vb = reinterpret_cast<const float4*>(xb + (size_t)row * D_MODEL)[t];
  float4 v;
  v.x = fminf(fmaxf(va.x + vb.x, -5.0f), 5.0f);
  v.y = fminf(fmaxf(va.y + vb.y, -5.0f), 5.0f);
  v.z = fminf(fmaxf(va.z + vb.z, -5.0f), 5.0f);
  v.w = fminf(fmaxf(va.w + vb.w, -5.0f), 5.0f);
  float s  = v.x + v.y + v.z + v.w;
  float s2 = v.x * v.x + v.y * v.y + v.z * v.z + v.w * v.w;
  #pragma unroll
  for (int o = 32; o > 0; o >>= 1) {
    s  += __shfl_down(s, o);
    s2 += __shfl_down(s2, o);
  }
  __shared__ float ls[4], ls2[4];
  const int wid = t >> 6, lid = t & 63;
  if (lid == 0) { ls[wid] = s; ls2[wid] = s2; }
  __syncthreads();
  if (t == 0) {
    ls[0]  = ls[0] + ls[1] + ls[2] + ls[3];
    ls2[0] = ls2[0] + ls2[1] + ls2[2] + ls2[3];
  }
  __syncthreads();
  const float mean = ls[0] * (1.0f / D_MODEL);
  const float var  = ls2[0] * (1.0f / D_MODEL) - mean * mean;
  const float rstd = rsqrtf(var + 1e-5f);
  float4 gv = reinterpret_cast<const float4*>(g)[t];
  float4 bv = reinterpret_cast<const float4*>(b)[t];
  float4 o;
  o.x = (v.x - mean) * rstd * gv.x + bv.x;
  o.y = (v.y - mean) * rstd * gv.y + bv.y;
  o.z = (v.z - mean) * rstd * gv.z + bv.z;
  o.w = (v.w - mean) * rstd * gv.w + bv.w;
  reinterpret_cast<float4*>(y + (size_t)row * D_MODEL)[t] = o;
}

// ---------------------------------------------------------------- GEMM
// 256x256 tile, 8 waves (2M x 4N, per-wave 128x64).  Round-3 sync
// skeleton (2 barriers + 2 counted vmcnt per K-tile).
//
// NEW (round 8): the GEMM is LDS-BANDWIDTH-bound (measured 45% MfmaUtil
// = predicted 47% cap from 256KB LDS traffic/K-tile vs 931 MFMA cy).
// For 3-combo, B's plane-1 is moved OUT of LDS: bf[nt][1] is a per-lane
// 16B global load (L1/L2-hot weight lines, 16 rows x fully-used 64B).
// B LDS rows shrink to 64B (plane-0 only) with chunk XOR (r>>2)&3 —
// uniform bank spread (8 granules/quad), conflict-free.  LDS traffic
// 256->208 KB/K-tile => cap 57%.  MFMA clusters ordered a0b0, a1b0,
// a0b1 so 32 LDS-fed MFMAs cover the b1 L2 latency.
//   THREE: G1 = {A-h0(2), B-all(2)} = 4 -> end-A vmcnt(4); G2 = {A-h1(2)}
//          -> end-B vmcnt(2).  b1 loads issue at phase-A top BEFORE
//          staging (memory clobber pins order) so the compiler's
//          auto-wait for them leaves staging in flight.
//   1-combo: unchanged (G1=6 -> vmcnt(6), G2=2 -> vmcnt(2)).
// NO XCD swizzle (round-4: FETCH x2, dur +75%).  NO full-burst prefetch
// (round-5: -4.5%).
#define MFMA(a, b, c) __builtin_amdgcn_mfma_f32_16x16x32_bf16(a, b, c, 0, 0, 0)
#define LD8(base, rb, c) \
  (*reinterpret_cast<const short8*>((base) + (rb) + ((c) << 3)))

template<bool THREE, bool OUT16>
__device__ __forceinline__ void gemm_body(
    const u16* __restrict__ A0, const u16* __restrict__ A1,
    const u16* __restrict__ B0, const u16* __restrict__ B1,
    void* __restrict__ outp, int ld, int K, int Kld, int koff,
    int m0, int n0, int doclip, u16* sm)
{
  const int t = threadIdx.x;
  const int w = t >> 6, l = t & 63;
  const int wr = w >> 2, wc = w & 3;          // 2M x 4N waves
  const int q = l >> 4, m16 = l & 15;
  constexpr int KSTEP = THREE ? 32 : 64;
  const int NK = K / KSTEP;

  // A staging lane geometry (8 rows x 128B per gload): lane l covers
  // row l>>3, phys chunk l&7; logical chunk = (l&7) ^ (row&7).
  const int arow = l >> 3, ac = l & 7;
  const int lc = ac ^ arow;
  const int coffA = THREE ? ((lc & 3) << 3) : (lc << 3);
  const u16* const Asrc = (THREE && (lc & 4)) ? A1 : A0;

  auto stageA = [&](int kt, int half) {       // half0: rows {0-63,128-191}
    const int kk = kt * KSTEP + koff + coffA;
    u16* dbuf = sm + (size_t)(kt & 1) * 32768;
    #pragma unroll
    for (int j = 0; j < 2; j++) {
      const int gi = (j * 8 + w) * 8 + arow;
      const int r = ((gi & 63) | ((gi >> 6) << 7)) + half * 64;
      gload16(Asrc + (size_t)(m0 + r) * Kld + kk, dbuf + (r & ~7) * 64);
    }
  };
  // 1-combo B staging: 128B rows, 8-chunk swizzle (as before)
  auto stageB = [&](int kt, int half) {       // half0: rows bit5==0
    const int kk = kt * KSTEP + koff + (lc << 3);
    u16* dbuf = sm + (size_t)(kt & 1) * 32768 + 16384;
    #pragma unroll
    for (int j = 0; j < 2; j++) {
      const int gi = (j * 8 + w) * 8 + arow;
      const int r = ((gi & 31) | ((gi >> 5) << 6)) + half * 32;
      gload16(B0 + (size_t)(n0 + r) * Kld + kk, dbuf + (r & ~7) * 64);
    }
  };
  // 3-combo B staging: plane-0 only, 64B rows, chunk XOR (r>>2)&3.
  // One gload = 16 rows x 64B; lane l: row (l>>2), phys chunk l&3.
  auto stageB3 = [&](int kt) {
    const int kk = kt * KSTEP + koff;
    u16* dbuf = sm + (size_t)(kt & 1) * 32768 + 16384;
    #pragma unroll
    for (int j = 0; j < 2; j++) {
      const int r = j * 128 + w * 16 + (l >> 2);           // 0..255
      const int lcB = (l & 3) ^ ((r >> 2) & 3);
      gload16(B0 + (size_t)(n0 + r) * Kld + kk + lcB * 8,
              dbuf + (size_t)(j * 128 + w * 16) * 32);
    }
  };

  f32x4 acc[8][4];
  #pragma unroll
  for (int i = 0; i < 8; i++)
    #pragma unroll
    for (int j = 0; j < 4; j++) acc[i][j] = (f32x4)(0.0f);

  // prologue: G1(0) then G2(0); leave G2(0) flying
  if constexpr (THREE) { stageA(0, 0); stageB3(0); }
  else                 { stageA(0, 0); stageB(0, 0); stageB(0, 1); }
  stageA(0, 1);                               // G2(0)
  VMCNT2();
  BARRIER();

  short8 af[4][2], bf[4][2];

  for (int k = 0; k < NK; ++k) {
    const u16* sA = sm + (size_t)(k & 1) * 32768;
    const u16* sB = sA + 16384;
    const bool pf = (k + 1 < NK);

    // ================= phase A: mh0 (rows wr*128 .. +64) =================
    if constexpr (THREE) {                    // b1 frags from global (plane 1)
      const int kkp = k * KSTEP + koff;
      #pragma unroll
      for (int nt = 0; nt < 4; nt++) {
        const int r = wc * 64 + nt * 16 + m16;
        bf[nt][1] = *reinterpret_cast<const short8*>(
            B1 + (size_t)(n0 + r) * Kld + kkp + q * 8);
      }
      asm volatile("" ::: "memory");          // keep b1 issue before staging
    }
    if (pf) {                                 // G1(k+1)
      stageA(k + 1, 0);
      if constexpr (THREE) stageB3(k + 1);
      else { stageB(k + 1, 0); stageB(k + 1, 1); }
    }
    #pragma unroll
    for (int mt = 0; mt < 4; mt++) {
      const int r = wr * 128 + mt * 16 + m16, rb = r * 64, rx = r & 7;
      af[mt][0] = LD8(sA, rb, q ^ rx);
      af[mt][1] = LD8(sA, rb, (4 + q) ^ rx);
    }
    #pragma unroll
    for (int nt = 0; nt < 4; nt++) {
      const int r = wc * 64 + nt * 16 + m16;
      if constexpr (THREE)
        bf[nt][0] = *reinterpret_cast<const short8*>(
            sB + r * 32 + ((q ^ ((r >> 2) & 3)) << 3));
      else {
        const int rb = r * 64, rx = r & 7;
        bf[nt][0] = LD8(sB, rb, q ^ rx);
        bf[nt][1] = LD8(sB, rb, (4 + q) ^ rx);
      }
    }
    __builtin_amdgcn_s_setprio(1);
    if constexpr (THREE) {
      #pragma unroll
      for (int mt = 0; mt < 4; mt++)          // a0*b0 (LDS-fed)
        #pragma unroll
        for (int nt = 0; nt < 4; nt++)
          acc[mt][nt] = MFMA(af[mt][0], bf[nt][0], acc[mt][nt]);
      #pragma unroll
      for (int mt = 0; mt < 4; mt++)          // a1*b0 (LDS-fed)
        #pragma unroll
        for (int nt = 0; nt < 4; nt++)
          acc[mt][nt] = MFMA(af[mt][1], bf[nt][0], acc[mt][nt]);
      #pragma unroll
      for (int mt = 0; mt < 4; mt++)          // a0*b1 (global-fed, covered)
        #pragma unroll
        for (int nt = 0; nt < 4; nt++)
          acc[mt][nt] = MFMA(af[mt][0], bf[nt][1], acc[mt][nt]);
    } else {
      #pragma unroll
      for (int mt = 0; mt < 4; mt++)
        #pragma unroll
        for (int nt = 0; nt < 4; nt++) {
          f32x4 c = acc[mt][nt];
          c = MFMA(af[mt][0], bf[nt][0], c);
          c = MFMA(af[mt][1], bf[nt][1], c);
          acc[mt][nt] = c;
        }
    }
    __builtin_amdgcn_s_setprio(0);
    if (pf) { if constexpr (THREE) VMCNT4(); else VMCNT6(); }
    else VMCNT0();                            // G2(k) resident
    BARRIER();

    // ================= phase B: mh1 (rows wr*128+64 .. +128) =============
    #pragma unroll
    for (int mt = 0; mt < 4; mt++) {
      const int r = wr * 128 + 64 + mt * 16 + m16, rb = r * 64, rx = r & 7;
      af[mt][0] = LD8(sA, rb, q ^ rx);
      af[mt][1] = LD8(sA, rb, (4 + q) ^ rx);
    }
    if (pf) stageA(k + 1, 1);                 // G2(k+1)
    __builtin_amdgcn_s_setprio(1);
    if constexpr (THREE) {
      #pragma unroll
      for (int mt = 0; mt < 4; mt++)
        #pragma unroll
        for (int nt = 0; nt < 4; nt++)
          acc[4 + mt][nt] = MFMA(af[mt][0], bf[nt][0], acc[4 + mt][nt]);
      #pragma unroll
      for (int mt = 0; mt < 4; mt++)
        #pragma unroll
        for (int nt = 0; nt < 4; nt++)
          acc[4 + mt][nt] = MFMA(af[mt][1], bf[nt][0], acc[4 + mt][nt]);
      #pragma unroll
      for (int mt = 0; mt < 4; mt++)
        #pragma unroll
        for (int nt = 0; nt < 4; nt++)
          acc[4 + mt][nt] = MFMA(af[mt][0], bf[nt][1], acc[4 + mt][nt]);
    } else {
      #pragma unroll
      for (int mt = 0; mt < 4; mt++)
        #pragma unroll
        for (int nt = 0; nt < 4; nt++) {
          f32x4 c = acc[4 + mt][nt];
          c = MFMA(af[mt][0], bf[nt][0], c);
          c = MFMA(af[mt][1], bf[nt][1], c);
          acc[4 + mt][nt] = c;
        }
    }
    __builtin_amdgcn_s_setprio(0);
    if (pf) {
      VMCNT2();                               // G1(k+1) resident
      BARRIER();
    }
  }

  // epilogue: C/D layout col=lane&15, row=(lane>>4)*4+reg; out pointer
  // pre-offset by block column (block never straddles the split).
  #pragma unroll
  for (int mt = 0; mt < 8; mt++) {
    #pragma unroll
    for (int nt = 0; nt < 4; nt++) {
      const int col = wc * 64 + nt * 16 + m16;
      #pragma unroll
      for (int r = 0; r < 4; r++) {
        const int row = m0 + wr * 128 + mt * 16 + q * 4 + r;
        float v = acc[mt][nt][r];
        if (doclip) v = fminf(fmaxf(v, -5.0f), 5.0f);
        if constexpr (OUT16)
          ((u16*)outp)[(size_t)row * ld + col] = bf_rn(v);
        else
          ((float*)outp)[(size_t)row * ld + col] = v;
      }
    }
  }
}

// GEMM1: x_proj = clip(xn @ W_in^T); cols <1536 (x_ssm) 1-combo -> RTN
// bf16 single plane; gate half 3-combo -> fp32.  Heavy-first ordering.
__global__ __launch_bounds__(512, 2) void gemm1_kernel(
    const u16* __restrict__ A0, const u16* __restrict__ A1,
    const u16* __restrict__ B0, const u16* __restrict__ B1,
    u16* __restrict__ out16, float* __restrict__ outf)
{
  __shared__ u16 sm[2][32768];               // 128 KiB
  const int m0 = blockIdx.x * 256;
  const int nblk = (int)gridDim.y - 1 - (int)blockIdx.y;   // heavy-first
  const int n0 = nblk * 256;
  if (n0 >= D_INNER)
    gemm_body<true, false>(A0, A1, B0, B1, outf + (n0 - D_INNER), D_INNER,
                           D_MODEL, D_MODEL, 0, m0, n0, 1, &sm[0][0]);
  else
    gemm_body<false, true>(A0, A1, B0, B1, out16 + n0, D_INNER,
                           D_MODEL, D_MODEL, 0, m0, n0, 1, &sm[0][0]);
}

// GEMM2: out_pre partials = prod @ W_out^T, split-K=2 (unclipped fp32
// partials into outA/outB; ln_sum does clip(pa+pb) + LN).
__global__ __launch_bounds__(512, 2) void gemm2_kernel(
    const u16* __restrict__ P0, const u16* __restrict__ P1,
    const u16* __restrict__ V0, const u16* __restrict__ V1,
    float* __restrict__ outA, float* __restrict__ outB)
{
  __shared__ u16 sm[2][32768];
  const int m0 = blockIdx.x * 256;
  const int by = (int)blockIdx.y;
  const int kslice = by >> 2;
  const int n0 = (by & 3) * 256;
  float* o = (kslice ? outB : outA) + n0;
  gemm_body<true, false>(P0, P1, V0, V1, o, D_MODEL, 768, 1536, kslice * 768,
                         m0, n0, 0, &sm[0][0]);
}

// --------------------------------------------------------------- SSM scan
// x_ssm input is a single bf16 plane (u16); gate stays fp32.
__global__ __launch_bounds__(256) void scan_kernel(
    const u16* __restrict__ xssm, const float* __restrict__ gate,
    const float* __restrict__ A_log, const float* __restrict__ Bv,
    const float* __restrict__ Cv, u16* __restrict__ P0, u16* __restrict__ P1)
{
  const int gid = blockIdx.x * 256 + threadIdx.x;       // 0 .. 98303
  const int chunk = gid / (BATCH * D_INNER);            // 0..15
  const int rem = gid - chunk * (BATCH * D_INNER);
  const int b = rem / D_INNER;
  const int i = rem - b * D_INNER;

  float dec[D_STATE], bb[D_STATE], cc[D_STATE], h[D_STATE];
  #pragma unroll
  for (int s = 0; s < D_STATE; s++) {
    float al = A_log[i * D_STATE + s];
    al = fminf(fmaxf(al, -5.0f), 0.0f);
    float a = -__expf(al);
    a = fminf(fmaxf(a, -2.0f), -0.01f);
    dec[s] = a * 0.9f;
    bb[s]  = Bv[i * D_STATE + s] * 0.1f;
    cc[s]  = Cv[i * D_STATE + s];
    h[s]   = 0.0f;
  }

  const size_t base = (size_t)b * SEQ_L * D_INNER + i;
  const int tmain = chunk * SCAN_CL;
  const int tw = (tmain >= SCAN_W) ? (tmain - SCAN_W) : 0;

  for (int t0 = tw; t0 < tmain; t0 += 16) {
    float xv[16];
    #pragma unroll
    for (int j = 0; j < 16; j++)
      xv[j] = bf_f(xssm[base + (size_t)(t0 + j) * D_INNER]);
    #pragma unroll
    for (int j = 0; j < 16; j++) {
      const float x = xv[j];
      #pragma unroll
      for (int s = 0; s < D_STATE; s++) {
        h[s] = fmaf(h[s], dec[s], x * bb[s]);
        h[s] = fminf(fmaxf(h[s], -5.0f), 5.0f);
      }
    }
  }

  float xf[8], gf[8];
  #pragma unroll
  for (int j = 0; j < 8; j++) {
    xf[j] = bf_f(xssm[base + (size_t)(tmain + j) * D_INNER]);
    gf[j] = gate[base + (size_t)(tmain + j) * D_INNER];
  }
  for (int t0 = tmain; t0 < tmain + SCAN_CL; t0 += 8) {
    float xn[8], gn[8];
    if (t0 + 8 < tmain + SCAN_CL) {
      #pragma unroll
      for (int j = 0; j < 8; j++) {
        xn[j] = bf_f(xssm[base + (size_t)(t0 + 8 + j) * D_INNER]);
        gn[j] = gate[base + (size_t)(t0 + 8 + j) * D_INNER];
      }
    }
    #pragma unroll
    for (int j = 0; j < 8; j++) {
      const float x = xf[j];
      float y = 0.0f;
      #pragma unroll
      for (int s = 0; s < D_STATE; s++) {
        h[s] = fmaf(h[s], dec[s], x * bb[s]);
        h[s] = fminf(fmaxf(h[s], -5.0f), 5.0f);
        y = fmaf(h[s], cc[s], y);
      }
      y = fminf(fmaxf(y, -5.0f), 5.0f);
      const float e  = __expf(2.0f * gf[j]);
      const float th = __fdividef(e - 1.0f, e + 1.0f);
      const float p = y * th;
      const u16 h0 = bf_rn(p);
      const u16 h1 = bf_rn(p - bf_f(h0));
      P0[base + (size_t)(t0 + j) * D_INNER] = h0;
      P1[base + (size_t)(t0 + j) * D_INNER] = h1;
    }
    #pragma unroll
    for (int j = 0; j < 8; j++) { xf[j] = xn[j]; gf[j] = gn[j]; }
  }
}

// ---------------------------------------------------------------- launcher
extern "C" void kernel_launch(void* const* d_in, const int* in_sizes, int n_in,
                              void* d_out, int out_size, void* d_ws, size_t ws_size,
                              hipStream_t stream)
{
  const float* x        = (const float*)d_in[0];
  const float* W_in     = (const float*)d_in[1];
  const float* W_out    = (const float*)d_in[2];
  const float* A_log    = (const float*)d_in[3];
  const float* Bmat     = (const float*)d_in[4];
  const float* Cmat     = (const float*)d_in[5];
  const float* ln_in_g  = (const float*)d_in[6];
  const float* ln_in_b  = (const float*)d_in[7];
  const float* ln_out_g = (const float*)d_in[8];
  const float* ln_out_b = (const float*)d_in[9];
  float* out = (float*)d_out;

  // workspace layout (bytes):
  // [xssm16 (in 50331648 region)][gate 50331648][xn0][xn1][B0][B1]
  // [gap][V0][V1]; P0/P1 overlay xn0..B1 (dead after gemm1); GEMM2
  // partials: outA overlays xssm16 region, outB overlays gate.
  char* ws = (char*)d_ws;
  u16*   xssm16 = (u16*)(ws);
  float* gate = (float*)(ws + 50331648);
  u16* xn0 = (u16*)(ws + 100663296);
  u16* xn1 = (u16*)(ws + 117440512);
  u16* B0  = (u16*)(ws + 134217728);
  u16* B1  = (u16*)(ws + 140509184);
  u16* V0  = (u16*)(ws + 153092096);
  u16* V1  = (u16*)(ws + 156237824);
  u16* P0  = (u16*)(ws + 100663296);
  u16* P1  = P0 + (size_t)MROWS * D_INNER;
  float* outA = (float*)(ws);
  float* outB = gate;

  // 0+1) fused: LN-in split rows + weight splits (x4 vectorized)
  {
    const int n14 = (2 * D_INNER * D_MODEL) / 4;   // W_in float4 count
    const int n24 = (D_MODEL * D_INNER) / 4;       // W_out float4 count
    const int wblocks = (n14 + n24 + 255) / 256;   // 4608
    prep_kernel<<<MROWS + wblocks, 256, 0, stream>>>(
        x, ln_in_g, ln_in_b, xn0, xn1, W_in, B0, B1, n14, W_out, V0, V1, n24);
  }

  // 2) x_proj = clip(xn @ W_in^T); x_ssm -> RTN bf16 plane, gate -> fp32.
  gemm1_kernel<<<dim3(MROWS / 256, (2 * D_INNER) / 256), 512, 0, stream>>>(
      xn0, xn1, B0, B1, xssm16, gate);

  // 3) chunked SSM scan -> prod as 2-term bf16
  scan_kernel<<<(BATCH * D_INNER * SCAN_C) / 256, 256, 0, stream>>>(
      xssm16, gate, A_log, Bmat, Cmat, P0, P1);

  // 4) out_pre = prod @ W_out^T, split-K=2 -> fp32 partials outA/outB
  gemm2_kernel<<<dim3(MROWS / 256, 2 * (D_MODEL / 256)), 512, 0, stream>>>(
      P0, P1, V0, V1, outA, outB);

  // 5) LayerNorm over clip(outA + outB) -> d_out
  ln_sum_kernel<<<MROWS, 256, 0, stream>>>(outA, outB, ln_out_g, ln_out_b, out);
}

// Round 9
// 318.309 us; speedup vs baseline: 1.0537x; 1.0537x over previous
//
#include <hip/hip_runtime.h>
#include <cstddef>
#include <cstdint>

#define D_MODEL 1024
#define D_STATE 8
#define D_INNER 1536
#define SEQ_L   2048
#define BATCH   4
#define MROWS   (BATCH * SEQ_L)   // 8192

// chunked scan: 32 chunks of 64, warmup 64 (|decay|<=0.55 -> 0.55^64 ~ 2e-17)
#define SCAN_CL 64
#define SCAN_W  64
#define SCAN_C  (SEQ_L / SCAN_CL)   // 32

typedef __attribute__((ext_vector_type(8))) short short8;
typedef __attribute__((ext_vector_type(4))) float f32x4;
typedef unsigned int u32;
typedef unsigned short u16;

__device__ __forceinline__ u16 bf_rn(float x) {   // fp32 -> bf16, round-nearest-even
  u32 b = __float_as_uint(x);
  return (u16)((b + 0x7FFFu + ((b >> 16) & 1u)) >> 16);
}
__device__ __forceinline__ float bf_f(u16 h) {
  return __uint_as_float(((u32)h) << 16);
}
__device__ __forceinline__ void gload16(const void* g, void* l) {
  __builtin_amdgcn_global_load_lds((const __attribute__((address_space(1))) u32*)g,
                                   (__attribute__((address_space(3))) u32*)l, 16, 0, 0);
}

#define VMCNT0() asm volatile("s_waitcnt vmcnt(0)" ::: "memory")
#define VMCNT2() asm volatile("s_waitcnt vmcnt(2)" ::: "memory")
#define VMCNT6() asm volatile("s_waitcnt vmcnt(6)" ::: "memory")
#define BARRIER()                                    \
  {                                                  \
    asm volatile("" ::: "memory");                   \
    __builtin_amdgcn_s_barrier();                    \
    asm volatile("" ::: "memory");                   \
  }

// --------------------------------------------- prep: LN-in split + weight split
// blockIdx.x < MROWS  : ln_split row
// blockIdx.x >= MROWS : weight-split, VECTORIZED x4 (float4 in, 2x ushort4 out)
__global__ __launch_bounds__(256) void prep_kernel(
    const float* __restrict__ x, const float* __restrict__ g,
    const float* __restrict__ b, u16* __restrict__ y0, u16* __restrict__ y1,
    const float* __restrict__ W1, u16* __restrict__ a0, u16* __restrict__ a1,
    int n14, const float* __restrict__ W2, u16* __restrict__ c0,
    u16* __restrict__ c1, int n24)
{
  const int bx = blockIdx.x;
  const int t = threadIdx.x;
  if (bx >= MROWS) {                      // ---- weight split (x4 vector) ----
    int i4 = (bx - MROWS) * 256 + t;
    const float* src;
    u16 *d0, *d1;
    int idx;
    if (i4 < n14)           { src = W1; d0 = a0; d1 = a1; idx = i4; }
    else if (i4 < n14 + n24){ src = W2; d0 = c0; d1 = c1; idx = i4 - n14; }
    else return;
    float4 v = reinterpret_cast<const float4*>(src)[idx];
    ushort4 h0, h1;
    u16 a;
    a = bf_rn(v.x); h0.x = a; h1.x = bf_rn(v.x - bf_f(a));
    a = bf_rn(v.y); h0.y = a; h1.y = bf_rn(v.y - bf_f(a));
    a = bf_rn(v.z); h0.z = a; h1.z = bf_rn(v.z - bf_f(a));
    a = bf_rn(v.w); h0.w = a; h1.w = bf_rn(v.w - bf_f(a));
    reinterpret_cast<ushort4*>(d0)[idx] = h0;
    reinterpret_cast<ushort4*>(d1)[idx] = h1;
    return;
  }
  // ---- LayerNorm-in -> 2-term bf16 planes ----
  const int row = bx;
  float4 v = reinterpret_cast<const float4*>(x + (size_t)row * D_MODEL)[t];
  float s  = v.x + v.y + v.z + v.w;
  float s2 = v.x * v.x + v.y * v.y + v.z * v.z + v.w * v.w;
  #pragma unroll
  for (int o = 32; o > 0; o >>= 1) {
    s  += __shfl_down(s, o);
    s2 += __shfl_down(s2, o);
  }
  __shared__ float ls[4], ls2[4];
  const int wid = t >> 6, lid = t & 63;
  if (lid == 0) { ls[wid] = s; ls2[wid] = s2; }
  __syncthreads();
  if (t == 0) {
    ls[0]  = ls[0] + ls[1] + ls[2] + ls[3];
    ls2[0] = ls2[0] + ls2[1] + ls2[2] + ls2[3];
  }
  __syncthreads();
  const float mean = ls[0] * (1.0f / D_MODEL);
  const float var  = ls2[0] * (1.0f / D_MODEL) - mean * mean;
  const float rstd = rsqrtf(var + 1e-5f);
  float4 gv = reinterpret_cast<const float4*>(g)[t];
  float4 bv = reinterpret_cast<const float4*>(b)[t];
  float o[4];
  o[0] = (v.x - mean) * rstd * gv.x + bv.x;
  o[1] = (v.y - mean) * rstd * gv.y + bv.y;
  o[2] = (v.z - mean) * rstd * gv.z + bv.z;
  o[3] = (v.w - mean) * rstd * gv.w + bv.w;
  ushort4 h0, h1;
  u16 a, c;
  a = bf_rn(o[0]); c = bf_rn(o[0] - bf_f(a)); h0.x = a; h1.x = c;
  a = bf_rn(o[1]); c = bf_rn(o[1] - bf_f(a)); h0.y = a; h1.y = c;
  a = bf_rn(o[2]); c = bf_rn(o[2] - bf_f(a)); h0.z = a; h1.z = c;
  a = bf_rn(o[3]); c = bf_rn(o[3] - bf_f(a)); h0.w = a; h1.w = c;
  reinterpret_cast<ushort4*>(y0 + (size_t)row * D_MODEL)[t] = h0;
  reinterpret_cast<ushort4*>(y1 + (size_t)row * D_MODEL)[t] = h1;
}

// LN over clip(pa+pb) — fuses GEMM2's split-K reduction + clip epilogue.
__global__ __launch_bounds__(256) void ln_sum_kernel(
    const float* __restrict__ xa, const float* __restrict__ xb,
    const float* __restrict__ g, const float* __restrict__ b,
    float* __restrict__ y)
{
  const int row = blockIdx.x;
  const int t = threadIdx.x;
  float4 va = reinterpret_cast<const float4*>(xa + (size_t)row * D_MODEL)[t];
  float4 vb = reinterpret_cast<const float4*>(xb + (size_t)row * D_MODEL)[t];
  float4 v;
  v.x = fminf(fmaxf(va.x + vb.x, -5.0f), 5.0f);
  v.y = fminf(fmaxf(va.y + vb.y, -5.0f), 5.0f);
  v.z = fminf(fmaxf(va.z + vb.z, -5.0f), 5.0f);
  v.w = fminf(fmaxf(va.w + vb.w, -5.0f), 5.0f);
  float s  = v.x + v.y + v.z + v.w;
  float s2 = v.x * v.x + v.y * v.y + v.z * v.z + v.w * v.w;
  #pragma unroll
  for (int o = 32; o > 0; o >>= 1) {
    s  += __shfl_down(s, o);
    s2 += __shfl_down(s2, o);
  }
  __shared__ float ls[4], ls2[4];
  const int wid = t >> 6, lid = t & 63;
  if (lid == 0) { ls[wid] = s; ls2[wid] = s2; }
  __syncthreads();
  if (t == 0) {
    ls[0]  = ls[0] + ls[1] + ls[2] + ls[3];
    ls2[0] = ls2[0] + ls2[1] + ls2[2] + ls2[3];
  }
  __syncthreads();
  const float mean = ls[0] * (1.0f / D_MODEL);
  const float var  = ls2[0] * (1.0f / D_MODEL) - mean * mean;
  const float rstd = rsqrtf(var + 1e-5f);
  float4 gv = reinterpret_cast<const float4*>(g)[t];
  float4 bv = reinterpret_cast<const float4*>(b)[t];
  float4 o;
  o.x = (v.x - mean) * rstd * gv.x + bv.x;
  o.y = (v.y - mean) * rstd * gv.y + bv.y;
  o.z = (v.z - mean) * rstd * gv.z + bv.z;
  o.w = (v.w - mean) * rstd * gv.w + bv.w;
  reinterpret_cast<float4*>(y + (size_t)row * D_MODEL)[t] = o;
}

// ---------------------------------------------------------------- GEMM
// 256x256 tile, 8 waves (2M x 4N, per-wave 128x64), BK=64 (1-combo) /
// BK=32 packed-planes (3-combo).  ROUND-3/7 schedule — the measured
// best of 7 structural variants (95.4-95.9 us, MfmaUtil 45%):
//   phase A: issue G1(k+1)={A-h0,B-h0,B-h1} (6 loads); read mh0 frags;
//            32/48 MFMA; vmcnt(6) [G2(k) resident]; barrier
//   phase B: read mh1 A-frags; issue G2(k+1)={A-h1} (2 loads);
//            32/48 MFMA; vmcnt(2) [G1(k+1) resident]; barrier
// Rejected by measurement: XCD swizzle (r4: FETCH x2, +75%), full-burst
// prefetch (r5: -4.5%), B-plane-1 via global (r8: +17%, bank conflicts
// + vmcnt-queue pollution).  OUT16: epilogue stores RTN-bf16.
#define MFMA(a, b, c) __builtin_amdgcn_mfma_f32_16x16x32_bf16(a, b, c, 0, 0, 0)
#define LD8(base, rb, c) \
  (*reinterpret_cast<const short8*>((base) + (rb) + ((c) << 3)))

template<bool THREE, bool OUT16>
__device__ __forceinline__ void gemm_body(
    const u16* __restrict__ A0, const u16* __restrict__ A1,
    const u16* __restrict__ B0, const u16* __restrict__ B1,
    void* __restrict__ outp, int ld, int K, int Kld, int koff,
    int m0, int n0, int doclip, u16* sm)
{
  const int t = threadIdx.x;
  const int w = t >> 6, l = t & 63;
  const int wr = w >> 2, wc = w & 3;          // 2M x 4N waves
  const int q = l >> 4, m16 = l & 15;
  constexpr int KSTEP = THREE ? 32 : 64;
  const int NK = K / KSTEP;

  // staging lane geometry: one gload = 8 rows x 128B, lane l covers
  // row l>>3, phys chunk l&7; logical chunk = (l&7) ^ (row&7).
  const int arow = l >> 3, ac = l & 7;
  const int lc = ac ^ arow;
  const int coff = THREE ? ((lc & 3) << 3) : (lc << 3);
  const u16* const Asrc = (THREE && (lc & 4)) ? A1 : A0;
  const u16* const Bsrc = (THREE && (lc & 4)) ? B1 : B0;

  auto stageA = [&](int kt, int half) {       // half0: rows {0-63,128-191}
    const int kk = kt * KSTEP + koff + coff;
    u16* dbuf = sm + (size_t)(kt & 1) * 32768;
    #pragma unroll
    for (int j = 0; j < 2; j++) {
      const int gi = (j * 8 + w) * 8 + arow;
      const int r = ((gi & 63) | ((gi >> 6) << 7)) + half * 64;
      gload16(Asrc + (size_t)(m0 + r) * Kld + kk, dbuf + (r & ~7) * 64);
    }
  };
  auto stageB = [&](int kt, int half) {       // half0: rows bit5==0
    const int kk = kt * KSTEP + koff + coff;
    u16* dbuf = sm + (size_t)(kt & 1) * 32768 + 16384;
    #pragma unroll
    for (int j = 0; j < 2; j++) {
      const int gi = (j * 8 + w) * 8 + arow;
      const int r = ((gi & 31) | ((gi >> 5) << 6)) + half * 32;
      gload16(Bsrc + (size_t)(n0 + r) * Kld + kk, dbuf + (r & ~7) * 64);
    }
  };

  f32x4 acc[8][4];
  #pragma unroll
  for (int i = 0; i < 8; i++)
    #pragma unroll
    for (int j = 0; j < 4; j++) acc[i][j] = (f32x4)(0.0f);

  // prologue: G1(0) then G2(0); vmcnt(2) -> G1(0) resident, G2(0) flying
  stageA(0, 0); stageB(0, 0); stageB(0, 1);   // G1(0)
  stageA(0, 1);                               // G2(0)
  VMCNT2();
  BARRIER();

  short8 af[4][2], bf[4][2];

  for (int k = 0; k < NK; ++k) {
    const u16* sA = sm + (size_t)(k & 1) * 32768;
    const u16* sB = sA + 16384;
    const bool pf = (k + 1 < NK);

    // ================= phase A: mh0 (rows wr*128 .. +64) =================
    if (pf) { stageA(k + 1, 0); stageB(k + 1, 0); stageB(k + 1, 1); }  // G1
    #pragma unroll
    for (int mt = 0; mt < 4; mt++) {
      const int r = wr * 128 + mt * 16 + m16, rb = r * 64, rx = r & 7;
      af[mt][0] = LD8(sA, rb, q ^ rx);
      af[mt][1] = LD8(sA, rb, (4 + q) ^ rx);
    }
    #pragma unroll
    for (int nt = 0; nt < 4; nt++) {
      const int r = wc * 64 + nt * 16 + m16, rb = r * 64, rx = r & 7;
      bf[nt][0] = LD8(sB, rb, q ^ rx);
      bf[nt][1] = LD8(sB, rb, (4 + q) ^ rx);
    }
    __builtin_amdgcn_s_setprio(1);
    #pragma unroll
    for (int mt = 0; mt < 4; mt++)
      #pragma unroll
      for (int nt = 0; nt < 4; nt++) {
        f32x4 c = acc[mt][nt];
        if (THREE) {
          c = MFMA(af[mt][0], bf[nt][0], c);
          c = MFMA(af[mt][0], bf[nt][1], c);
          c = MFMA(af[mt][1], bf[nt][0], c);
        } else {
          c = MFMA(af[mt][0], bf[nt][0], c);
          c = MFMA(af[mt][1], bf[nt][1], c);
        }
        acc[mt][nt] = c;
      }
    __builtin_amdgcn_s_setprio(0);
    if (pf) VMCNT6(); else VMCNT0();          // G2(k) resident
    BARRIER();

    // ================= phase B: mh1 (rows wr*128+64 .. +128) =============
    #pragma unroll
    for (int mt = 0; mt < 4; mt++) {
      const int r = wr * 128 + 64 + mt * 16 + m16, rb = r * 64, rx = r & 7;
      af[mt][0] = LD8(sA, rb, q ^ rx);
      af[mt][1] = LD8(sA, rb, (4 + q) ^ rx);
    }
    if (pf) stageA(k + 1, 1);                 // G2(k+1)
    __builtin_amdgcn_s_setprio(1);
    #pragma unroll
    for (int mt = 0; mt < 4; mt++)
      #pragma unroll
      for (int nt = 0; nt < 4; nt++) {
        f32x4 c = acc[4 + mt][nt];
        if (THREE) {
          c = MFMA(af[mt][0], bf[nt][0], c);
          c = MFMA(af[mt][0], bf[nt][1], c);
          c = MFMA(af[mt][1], bf[nt][0], c);
        } else {
          c = MFMA(af[mt][0], bf[nt][0], c);
          c = MFMA(af[mt][1], bf[nt][1], c);
        }
        acc[4 + mt][nt] = c;
      }
    __builtin_amdgcn_s_setprio(0);
    if (pf) {
      VMCNT2();                               // G1(k+1) resident
      BARRIER();
    }
  }

  // epilogue: C/D layout col=lane&15, row=(lane>>4)*4+reg; out pointer
  // pre-offset by block column (block never straddles the split).
  #pragma unroll
  for (int mt = 0; mt < 8; mt++) {
    #pragma unroll
    for (int nt = 0; nt < 4; nt++) {
      const int col = wc * 64 + nt * 16 + m16;
      #pragma unroll
      for (int r = 0; r < 4; r++) {
        const int row = m0 + wr * 128 + mt * 16 + q * 4 + r;
        float v = acc[mt][nt][r];
        if (doclip) v = fminf(fmaxf(v, -5.0f), 5.0f);
        if constexpr (OUT16)
          ((u16*)outp)[(size_t)row * ld + col] = bf_rn(v);
        else
          ((float*)outp)[(size_t)row * ld + col] = v;
      }
    }
  }
}

// GEMM1: x_proj = clip(xn @ W_in^T); cols <1536 (x_ssm) 1-combo -> RTN
// bf16 single plane; gate half 3-combo -> fp32.  Heavy-first ordering.
__global__ __launch_bounds__(512, 2) void gemm1_kernel(
    const u16* __restrict__ A0, const u16* __restrict__ A1,
    const u16* __restrict__ B0, const u16* __restrict__ B1,
    u16* __restrict__ out16, float* __restrict__ outf)
{
  __shared__ u16 sm[2][32768];               // 128 KiB
  const int m0 = blockIdx.x * 256;
  const int nblk = (int)gridDim.y - 1 - (int)blockIdx.y;   // heavy-first
  const int n0 = nblk * 256;
  if (n0 >= D_INNER)
    gemm_body<true, false>(A0, A1, B0, B1, outf + (n0 - D_INNER), D_INNER,
                           D_MODEL, D_MODEL, 0, m0, n0, 1, &sm[0][0]);
  else
    gemm_body<false, true>(A0, A1, B0, B1, out16 + n0, D_INNER,
                           D_MODEL, D_MODEL, 0, m0, n0, 1, &sm[0][0]);
}

// GEMM2: out_pre partials = prod @ W_out^T, split-K=2 (unclipped fp32
// partials into outA/outB; ln_sum does clip(pa+pb) + LN).
__global__ __launch_bounds__(512, 2) void gemm2_kernel(
    const u16* __restrict__ P0, const u16* __restrict__ P1,
    const u16* __restrict__ V0, const u16* __restrict__ V1,
    float* __restrict__ outA, float* __restrict__ outB)
{
  __shared__ u16 sm[2][32768];
  const int m0 = blockIdx.x * 256;
  const int by = (int)blockIdx.y;
  const int kslice = by >> 2;
  const int n0 = (by & 3) * 256;
  float* o = (kslice ? outB : outA) + n0;
  gemm_body<true, false>(P0, P1, V0, V1, o, D_MODEL, 768, 1536, kslice * 768,
                         m0, n0, 0, &sm[0][0]);
}

// --------------------------------------------------------------- SSM scan
// x_ssm input is a single bf16 plane (u16); gate stays fp32.
// 32 chunks of 64 (was 16x128): 12 waves/CU for latency hiding.
__global__ __launch_bounds__(256) void scan_kernel(
    const u16* __restrict__ xssm, const float* __restrict__ gate,
    const float* __restrict__ A_log, const float* __restrict__ Bv,
    const float* __restrict__ Cv, u16* __restrict__ P0, u16* __restrict__ P1)
{
  const int gid = blockIdx.x * 256 + threadIdx.x;       // 0 .. 196607
  const int chunk = gid / (BATCH * D_INNER);            // 0..31
  const int rem = gid - chunk * (BATCH * D_INNER);
  const int b = rem / D_INNER;
  const int i = rem - b * D_INNER;

  float dec[D_STATE], bb[D_STATE], cc[D_STATE], h[D_STATE];
  #pragma unroll
  for (int s = 0; s < D_STATE; s++) {
    float al = A_log[i * D_STATE + s];
    al = fminf(fmaxf(al, -5.0f), 0.0f);
    float a = -__expf(al);
    a = fminf(fmaxf(a, -2.0f), -0.01f);
    dec[s] = a * 0.9f;
    bb[s]  = Bv[i * D_STATE + s] * 0.1f;
    cc[s]  = Cv[i * D_STATE + s];
    h[s]   = 0.0f;
  }

  const size_t base = (size_t)b * SEQ_L * D_INNER + i;
  const int tmain = chunk * SCAN_CL;
  const int tw = (tmain >= SCAN_W) ? (tmain - SCAN_W) : 0;

  for (int t0 = tw; t0 < tmain; t0 += 16) {
    float xv[16];
    #pragma unroll
    for (int j = 0; j < 16; j++)
      xv[j] = bf_f(xssm[base + (size_t)(t0 + j) * D_INNER]);
    #pragma unroll
    for (int j = 0; j < 16; j++) {
      const float x = xv[j];
      #pragma unroll
      for (int s = 0; s < D_STATE; s++) {
        h[s] = fmaf(h[s], dec[s], x * bb[s]);
        h[s] = fminf(fmaxf(h[s], -5.0f), 5.0f);
      }
    }
  }

  float xf[8], gf[8];
  #pragma unroll
  for (int j = 0; j < 8; j++) {
    xf[j] = bf_f(xssm[base + (size_t)(tmain + j) * D_INNER]);
    gf[j] = gate[base + (size_t)(tmain + j) * D_INNER];
  }
  for (int t0 = tmain; t0 < tmain + SCAN_CL; t0 += 8) {
    float xn[8], gn[8];
    if (t0 + 8 < tmain + SCAN_CL) {
      #pragma unroll
      for (int j = 0; j < 8; j++) {
        xn[j] = bf_f(xssm[base + (size_t)(t0 + 8 + j) * D_INNER]);
        gn[j] = gate[base + (size_t)(t0 + 8 + j) * D_INNER];
      }
    }
    #pragma unroll
    for (int j = 0; j < 8; j++) {
      const float x = xf[j];
      float y = 0.0f;
      #pragma unroll
      for (int s = 0; s < D_STATE; s++) {
        h[s] = fmaf(h[s], dec[s], x * bb[s]);
        h[s] = fminf(fmaxf(h[s], -5.0f), 5.0f);
        y = fmaf(h[s], cc[s], y);
      }
      y = fminf(fmaxf(y, -5.0f), 5.0f);
      const float e  = __expf(2.0f * gf[j]);
      const float th = __fdividef(e - 1.0f, e + 1.0f);
      const float p = y * th;
      const u16 h0 = bf_rn(p);
      const u16 h1 = bf_rn(p - bf_f(h0));
      P0[base + (size_t)(t0 + j) * D_INNER] = h0;
      P1[base + (size_t)(t0 + j) * D_INNER] = h1;
    }
    #pragma unroll
    for (int j = 0; j < 8; j++) { xf[j] = xn[j]; gf[j] = gn[j]; }
  }
}

// ---------------------------------------------------------------- launcher
extern "C" void kernel_launch(void* const* d_in, const int* in_sizes, int n_in,
                              void* d_out, int out_size, void* d_ws, size_t ws_size,
                              hipStream_t stream)
{
  const float* x        = (const float*)d_in[0];
  const float* W_in     = (const float*)d_in[1];
  const float* W_out    = (const float*)d_in[2];
  const float* A_log    = (const float*)d_in[3];
  const float* Bmat     = (const float*)d_in[4];
  const float* Cmat     = (const float*)d_in[5];
  const float* ln_in_g  = (const float*)d_in[6];
  const float* ln_in_b  = (const float*)d_in[7];
  const float* ln_out_g = (const float*)d_in[8];
  const float* ln_out_b = (const float*)d_in[9];
  float* out = (float*)d_out;

  // workspace layout (bytes):
  // [xssm16 (in 50331648 region)][gate 50331648][xn0][xn1][B0][B1]
  // [gap][V0][V1]; P0/P1 overlay xn0..B1 (dead after gemm1); GEMM2
  // partials: outA overlays xssm16 region, outB overlays gate.
  char* ws = (char*)d_ws;
  u16*   xssm16 = (u16*)(ws);
  float* gate = (float*)(ws + 50331648);
  u16* xn0 = (u16*)(ws + 100663296);
  u16* xn1 = (u16*)(ws + 117440512);
  u16* B0  = (u16*)(ws + 134217728);
  u16* B1  = (u16*)(ws + 140509184);
  u16* V0  = (u16*)(ws + 153092096);
  u16* V1  = (u16*)(ws + 156237824);
  u16* P0  = (u16*)(ws + 100663296);
  u16* P1  = P0 + (size_t)MROWS * D_INNER;
  float* outA = (float*)(ws);
  float* outB = gate;

  // 0+1) fused: LN-in split rows + weight splits (x4 vectorized)
  {
    const int n14 = (2 * D_INNER * D_MODEL) / 4;   // W_in float4 count
    const int n24 = (D_MODEL * D_INNER) / 4;       // W_out float4 count
    const int wblocks = (n14 + n24 + 255) / 256;   // 4608
    prep_kernel<<<MROWS + wblocks, 256, 0, stream>>>(
        x, ln_in_g, ln_in_b, xn0, xn1, W_in, B0, B1, n14, W_out, V0, V1, n24);
  }

  // 2) x_proj = clip(xn @ W_in^T); x_ssm -> RTN bf16 plane, gate -> fp32.
  gemm1_kernel<<<dim3(MROWS / 256, (2 * D_INNER) / 256), 512, 0, stream>>>(
      xn0, xn1, B0, B1, xssm16, gate);

  // 3) chunked SSM scan -> prod as 2-term bf16 (32 chunks of 64)
  scan_kernel<<<(BATCH * D_INNER * SCAN_C) / 256, 256, 0, stream>>>(
      xssm16, gate, A_log, Bmat, Cmat, P0, P1);

  // 4) out_pre = prod @ W_out^T, split-K=2 -> fp32 partials outA/outB
  gemm2_kernel<<<dim3(MROWS / 256, 2 * (D_MODEL / 256)), 512, 0, stream>>>(
      P0, P1, V0, V1, outA, outB);

  // 5) LayerNorm over clip(outA + outB) -> d_out
  ln_sum_kernel<<<MROWS, 256, 0, stream>>>(outA, outB, ln_out_g, ln_out_b, out);
}